// Round 6
// baseline (105.347 us; speedup 1.0000x reference)
//
#include <hip/hip_runtime.h>
#include <math.h>

// NLM denoise: x [2,3,512,512] f32, SWS=11 (121 shifts), TWS=5, circular wrap.
// d2 = ||Pc||^2 + ||Ps||^2 - 2<Pc,Ps>; cross-terms via v_dot2_f32_f16 on f16
// pair table; norms via precomputed vertical 5-sum table V (K^2-prescaled).
// w = exp2(-sqrt(K2*d2)); out = clip(sum w*x / sum w, 0, 1)
// mc=2 outputs/thread, 512-thread blocks -> 4 waves/SIMD (occupancy round).

#define H_IMG 512
#define W_IMG 512
#define MASK  511
#define HWSZ  (H_IMG * W_IMG)
#define TILE  32
#define HALO  7
#define XD    46          // TILE + 2*HALO
#define YSTR  48          // padded col-stride for yf / ldsY2
#define HSTR  44          // col-stride for ldsH (42 cols used)
#define VSTR  44          // col-stride for ldsV (42 cols used)
#define NTHR  512

typedef _Float16 h2 __attribute__((ext_vector_type(2)));

__device__ __forceinline__ float fdot2(h2 a, h2 b, float c) {
#if __has_builtin(__builtin_amdgcn_fdot2)
    return __builtin_amdgcn_fdot2(a, b, c, false);
#else
    return c + (float)a.x * (float)b.x + (float)a.y * (float)b.y;
#endif
}

__device__ __forceinline__ float fast_exp2(float x) {
#if __has_builtin(__builtin_amdgcn_exp2f)
    return __builtin_amdgcn_exp2f(x);
#else
    return __expf(x * 0.6931471805599453f);
#endif
}

#define K2C   0.23126321070979063f    // (log2(e)/3)^2
#define N2K2 -0.46252642141958126f    // -2*K2C

__global__ __launch_bounds__(NTHR, 4)
void nlm_kernel(const float* __restrict__ x, float* __restrict__ out) {
    __shared__ float4   ldsX[XD * XD];        // 33856 B
    __shared__ float    ldsYf[XD * YSTR];     //  8832 B (f32 y, 47 cols used)
    __shared__ unsigned ldsY2[XD * YSTR];     //  8832 B (f16 pair (y_c,y_{c+1}))
    __shared__ float    ldsH[XD * HSTR];      //  8096 B (row 5-norms)
    __shared__ float    ldsV[42 * VSTR];      //  7392 B (K2 * vertical 5-sum of H)
                                              //  total 67008 B -> 2 blocks/CU

    const int n  = blockIdx.z;
    const int ti = blockIdx.y * TILE;
    const int tj = blockIdx.x * TILE;
    const int tx = threadIdx.x;            // 0..31
    const int ty = threadIdx.y;            // 0..15
    const int tid = ty * 32 + tx;

    const float* xb = x + (size_t)n * 3 * HWSZ;

    // ---- A: stage x (tile + halo 7), packed float4 ----
    for (int e = tid; e < XD * XD; e += NTHR) {
        int r = e / XD, c = e - r * XD;
        int gi = (ti + r - HALO) & MASK;
        int gj = (tj + c - HALO) & MASK;
        size_t o = (size_t)gi * W_IMG + gj;
        ldsX[e] = make_float4(xb[o], xb[o + HWSZ], xb[o + 2 * HWSZ], 0.f);
    }
    __syncthreads();

    // ---- B: luminance (f32), 46 rows x 47 cols (col 46 dup, masked later) ----
    for (int e = tid; e < XD * 47; e += NTHR) {
        int r = e / 47, c = e - r * 47;
        int cs = (c == 46) ? 45 : c;
        float4 v = ldsX[r * XD + cs];
        float rr = fminf(fmaxf(v.x, 0.f), 1.f);
        float gg = fminf(fmaxf(v.y, 0.f), 1.f);
        float bb = fminf(fmaxf(v.z, 0.f), 1.f);
        ldsYf[r * YSTR + c] = 0.299f * rr + 0.587f * gg + 0.114f * bb;
    }
    __syncthreads();

    // ---- C: f16 pair table: entry[r][c] = (y(c), y(c+1)) ----
    for (int e = tid; e < XD * XD; e += NTHR) {   // 46x46 entries
        int r = e / XD, c = e - r * XD;
        h2 p;
        p.x = (_Float16)ldsYf[r * YSTR + c];
        p.y = (_Float16)ldsYf[r * YSTR + c + 1];
        ldsY2[r * YSTR + c] = __builtin_bit_cast(unsigned, p);
    }
    __syncthreads();

    // ---- D: row-norm H(r,c) = sum_{d=0..4} yh(r,c+d)^2 ----
    for (int e = tid; e < XD * 42; e += NTHR) {
        int r = e / 42, c = e - r * 42;
        h2 a  = __builtin_bit_cast(h2, ldsY2[r * YSTR + c]);
        h2 b  = __builtin_bit_cast(h2, ldsY2[r * YSTR + c + 2]);
        h2 cc = __builtin_bit_cast(h2, ldsY2[r * YSTR + c + 4]);
        float x0 = (float)a.x, x1 = (float)a.y;
        float x2 = (float)b.x, x3 = (float)b.y;
        float x4 = (float)cc.x;
        ldsH[r * HSTR + c] = x0*x0 + x1*x1 + x2*x2 + x3*x3 + x4*x4;
    }
    __syncthreads();

    // ---- E: V(r,c) = K2 * sum_{t=0..4} H(r+t,c) ----
    for (int e = tid; e < 42 * 42; e += NTHR) {
        int r = e / 42, c = e - r * 42;
        const float* hp = &ldsH[r * HSTR + c];
        float s = ((hp[0] + hp[HSTR]) + (hp[2*HSTR] + hp[3*HSTR])) + hp[4*HSTR];
        ldsV[r * VSTR + c] = K2C * s;
    }
    __syncthreads();

    const int jl = tx + HALO;          // LDS col of this thread's column
    const int il = ty * 2 + HALO;      // LDS row of first of 2 outputs

    // center patch as f16 pairs (rows il-2..il+3) + K2-prescaled center norms
    h2 cyP[6][3];
    float Vc[2];
    #pragma unroll
    for (int t = 0; t < 6; ++t) {
        int base = (il - 2 + t) * YSTR + (jl - 2);
        cyP[t][0] = __builtin_bit_cast(h2, ldsY2[base]);
        cyP[t][1] = __builtin_bit_cast(h2, ldsY2[base + 2]);
        h2 z = __builtin_bit_cast(h2, ldsY2[base + 4]);
        z.y = (_Float16)0.f;
        cyP[t][2] = z;
    }
    Vc[0] = ldsV[(il - 2) * VSTR + (jl - 2)];
    Vc[1] = ldsV[(il - 1) * VSTR + (jl - 2)];

    float den[2]  = {0.f, 0.f};
    float num0[2] = {0.f, 0.f};
    float num1[2] = {0.f, 0.f};
    float num2[2] = {0.f, 0.f};

    #pragma unroll 1
    for (int xs = -5; xs <= 5; ++xs) {
        const int jc  = jl - xs - 2;   // shifted 5-window base col
        const int xjc = jl - xs;       // shifted x neighbor col (ldsX)

        h2     swP[6][3];              // shifted-y f16-pair ring over rows
        float  Wr[2];                  // V-table ring
        float4 xw[2];                  // x-neighbor ring

        #pragma unroll
        for (int t = 0; t < 6; ++t) {
            int base = (il - 7 + t) * YSTR + jc;
            swP[t][0] = __builtin_bit_cast(h2, ldsY2[base]);
            swP[t][1] = __builtin_bit_cast(h2, ldsY2[base + 2]);
            swP[t][2] = __builtin_bit_cast(h2, ldsY2[base + 4]);
        }
        Wr[0] = ldsV[(il - 7) * VSTR + jc];
        Wr[1] = ldsV[(il - 6) * VSTR + jc];
        xw[0] = ldsX[(il - 5) * XD + xjc];
        xw[1] = ldsX[(il - 4) * XD + xjc];

        #pragma unroll
        for (int k = 0; k <= 10; ++k) {     // ys = 5 - k
            // prefetch next step's ring entries
            h2 nsw0, nsw1, nsw2; float nWv; float4 nxw;
            if (k < 10) {
                int base = (il + k - 1) * YSTR + jc;
                nsw0 = __builtin_bit_cast(h2, ldsY2[base]);
                nsw1 = __builtin_bit_cast(h2, ldsY2[base + 2]);
                nsw2 = __builtin_bit_cast(h2, ldsY2[base + 4]);
                nWv  = ldsV[(il + k - 5) * VSTR + jc];
                nxw  = ldsX[(il + k - 3) * XD + xjc];
            }

            // row-dot cross terms (f16 MACs, f32 accumulate)
            float s[6];
            #pragma unroll
            for (int t = 0; t < 6; ++t) {
                const int m = (t + k) % 6;
                s[t] = fdot2(cyP[t][0], swP[m][0],
                       fdot2(cyP[t][1], swP[m][1],
                       fdot2(cyP[t][2], swP[m][2], 0.f)));
            }

            // sliding 5-row sums of cross terms
            float S0 = ((s[0] + s[1]) + (s[2] + s[3])) + s[4];
            float S1 = S0 - s[0] + s[5];

            float d2a0 = fmaf(N2K2, S0, Vc[0] + Wr[k & 1]);
            float d2a1 = fmaf(N2K2, S1, Vc[1] + Wr[(k + 1) & 1]);

            {
                float sd = __builtin_amdgcn_sqrtf(__builtin_fabsf(d2a0));
                float w  = fast_exp2(-sd);
                float4 xv = xw[k & 1];
                num0[0] = fmaf(w, xv.x, num0[0]);
                num1[0] = fmaf(w, xv.y, num1[0]);
                num2[0] = fmaf(w, xv.z, num2[0]);
                den[0] += w;
            }
            {
                float sd = __builtin_amdgcn_sqrtf(__builtin_fabsf(d2a1));
                float w  = fast_exp2(-sd);
                float4 xv = xw[(k + 1) & 1];
                num0[1] = fmaf(w, xv.x, num0[1]);
                num1[1] = fmaf(w, xv.y, num1[1]);
                num2[1] = fmaf(w, xv.z, num2[1]);
                den[1] += w;
            }

            // commit prefetched ring entries
            if (k < 10) {
                swP[k % 6][0] = nsw0;
                swP[k % 6][1] = nsw1;
                swP[k % 6][2] = nsw2;
                Wr[k & 1] = nWv;
                xw[k & 1] = nxw;
            }
        }
    }

    // ---- epilogue ----
    float* ob = out + (size_t)n * 3 * HWSZ;
    #pragma unroll
    for (int o = 0; o < 2; ++o) {
        int gi = ti + ty * 2 + o;
        int gj = tj + tx;
        size_t off = (size_t)gi * W_IMG + gj;
        float inv = __builtin_amdgcn_rcpf(den[o]);
        float v0 = fminf(fmaxf(num0[o] * inv, 0.f), 1.f);
        float v1 = fminf(fmaxf(num1[o] * inv, 0.f), 1.f);
        float v2 = fminf(fmaxf(num2[o] * inv, 0.f), 1.f);
        ob[off]            = v0;
        ob[off + HWSZ]     = v1;
        ob[off + 2 * HWSZ] = v2;
    }
}

extern "C" void kernel_launch(void* const* d_in, const int* in_sizes, int n_in,
                              void* d_out, int out_size, void* d_ws, size_t ws_size,
                              hipStream_t stream) {
    const float* x = (const float*)d_in[0];
    float* out = (float*)d_out;
    dim3 grid(W_IMG / TILE, H_IMG / TILE, 2);   // (16,16,2) = 512 blocks
    dim3 block(32, 16);                          // 512 threads, mc=2
    nlm_kernel<<<grid, block, 0, stream>>>(x, out);
}

// Round 7
// 98.422 us; speedup vs baseline: 1.0704x; 1.0704x over previous
//
#include <hip/hip_runtime.h>
#include <math.h>

// NLM denoise: x [2,3,512,512] f32, SWS=11 (121 shifts), TWS=5, circular wrap.
// d2 = ||Pc||^2 + ||Ps||^2 - 2<Pc,Ps>; cross-terms via v_dot2_f32_f16 on f16
// pair table; norms via precomputed vertical 5-sum table V (K^2-prescaled).
// w = exp2(-sqrt(K2*d2)); out = clip(sum w*x / sum w, 0, 1)
// mc=4, 256-thr blocks (2 waves/SIMD, thread-capped). Weight tail (sqrt/exp/
// acc) software-pipelined one k-step behind S/d2 to pull trans ops off the
// critical path; num0/num1 accumulated as packed f32 pairs (v_pk_fma_f32).

#define H_IMG 512
#define W_IMG 512
#define MASK  511
#define HWSZ  (H_IMG * W_IMG)
#define TILE  32
#define HALO  7
#define XD    46          // TILE + 2*HALO
#define YSTR  48          // padded col-stride for yf / ldsY2
#define HSTR  44          // col-stride for ldsH (42 cols used)
#define VSTR  44          // col-stride for ldsV (42 cols used)

typedef _Float16 h2 __attribute__((ext_vector_type(2)));
typedef float f32x2 __attribute__((ext_vector_type(2)));

__device__ __forceinline__ float fdot2(h2 a, h2 b, float c) {
#if __has_builtin(__builtin_amdgcn_fdot2)
    return __builtin_amdgcn_fdot2(a, b, c, false);
#else
    return c + (float)a.x * (float)b.x + (float)a.y * (float)b.y;
#endif
}

__device__ __forceinline__ float fast_exp2(float x) {
#if __has_builtin(__builtin_amdgcn_exp2f)
    return __builtin_amdgcn_exp2f(x);
#else
    return __expf(x * 0.6931471805599453f);
#endif
}

#define K2C   0.23126321070979063f    // (log2(e)/3)^2
#define N2K2 -0.46252642141958126f    // -2*K2C

__global__ __launch_bounds__(256, 2)
void nlm_kernel(const float* __restrict__ x, float* __restrict__ out) {
    __shared__ float4   ldsX[XD * XD];        // 33856 B
    __shared__ float    ldsYf[XD * YSTR];     //  8832 B (f32 y, 47 cols used)
    __shared__ unsigned ldsY2[XD * YSTR];     //  8832 B (f16 pair (y_c,y_{c+1}))
    __shared__ float    ldsH[XD * HSTR];      //  8096 B (row 5-norms)
    __shared__ float    ldsV[42 * VSTR];      //  7392 B (K2 * vertical 5-sum of H)
                                              //  total 67008 B -> 2 blocks/CU

    const int n  = blockIdx.z;
    const int ti = blockIdx.y * TILE;
    const int tj = blockIdx.x * TILE;
    const int tx = threadIdx.x;            // 0..31
    const int ty = threadIdx.y;            // 0..7
    const int tid = ty * 32 + tx;

    const float* xb = x + (size_t)n * 3 * HWSZ;

    // ---- A: stage x (tile + halo 7), packed float4 ----
    for (int e = tid; e < XD * XD; e += 256) {
        int r = e / XD, c = e - r * XD;
        int gi = (ti + r - HALO) & MASK;
        int gj = (tj + c - HALO) & MASK;
        size_t o = (size_t)gi * W_IMG + gj;
        ldsX[e] = make_float4(xb[o], xb[o + HWSZ], xb[o + 2 * HWSZ], 0.f);
    }
    __syncthreads();

    // ---- B: luminance (f32), 46 rows x 47 cols (col 46 dup, masked later) ----
    for (int e = tid; e < XD * 47; e += 256) {
        int r = e / 47, c = e - r * 47;
        int cs = (c == 46) ? 45 : c;
        float4 v = ldsX[r * XD + cs];
        float rr = fminf(fmaxf(v.x, 0.f), 1.f);
        float gg = fminf(fmaxf(v.y, 0.f), 1.f);
        float bb = fminf(fmaxf(v.z, 0.f), 1.f);
        ldsYf[r * YSTR + c] = 0.299f * rr + 0.587f * gg + 0.114f * bb;
    }
    __syncthreads();

    // ---- C: f16 pair table: entry[r][c] = (y(c), y(c+1)) ----
    for (int e = tid; e < XD * XD; e += 256) {   // 46x46 entries
        int r = e / XD, c = e - r * XD;
        h2 p;
        p.x = (_Float16)ldsYf[r * YSTR + c];
        p.y = (_Float16)ldsYf[r * YSTR + c + 1];
        ldsY2[r * YSTR + c] = __builtin_bit_cast(unsigned, p);
    }
    __syncthreads();

    // ---- D: row-norm H(r,c) = sum_{d=0..4} yh(r,c+d)^2 ----
    for (int e = tid; e < XD * 42; e += 256) {
        int r = e / 42, c = e - r * 42;
        h2 a  = __builtin_bit_cast(h2, ldsY2[r * YSTR + c]);
        h2 b  = __builtin_bit_cast(h2, ldsY2[r * YSTR + c + 2]);
        h2 cc = __builtin_bit_cast(h2, ldsY2[r * YSTR + c + 4]);
        float x0 = (float)a.x, x1 = (float)a.y;
        float x2 = (float)b.x, x3 = (float)b.y;
        float x4 = (float)cc.x;
        ldsH[r * HSTR + c] = x0*x0 + x1*x1 + x2*x2 + x3*x3 + x4*x4;
    }
    __syncthreads();

    // ---- E: V(r,c) = K2 * sum_{t=0..4} H(r+t,c) ----
    for (int e = tid; e < 42 * 42; e += 256) {
        int r = e / 42, c = e - r * 42;
        const float* hp = &ldsH[r * HSTR + c];
        float s = ((hp[0] + hp[HSTR]) + (hp[2*HSTR] + hp[3*HSTR])) + hp[4*HSTR];
        ldsV[r * VSTR + c] = K2C * s;
    }
    __syncthreads();

    const int jl = tx + HALO;          // LDS col of this thread's column
    const int il = ty * 4 + HALO;      // LDS row of first of 4 outputs

    // center patch as f16 pairs + K2-prescaled center norms (from V table)
    h2 cyP[8][3];
    float Vc[4];
    #pragma unroll
    for (int t = 0; t < 8; ++t) {
        int base = (il - 2 + t) * YSTR + (jl - 2);
        cyP[t][0] = __builtin_bit_cast(h2, ldsY2[base]);
        cyP[t][1] = __builtin_bit_cast(h2, ldsY2[base + 2]);
        h2 z = __builtin_bit_cast(h2, ldsY2[base + 4]);
        z.y = (_Float16)0.f;
        cyP[t][2] = z;
    }
    #pragma unroll
    for (int o = 0; o < 4; ++o)
        Vc[o] = ldsV[(il - 2 + o) * VSTR + (jl - 2)];

    f32x2 acc01[4];   // (num0, num1) packed
    float num2[4], den[4];
    #pragma unroll
    for (int o = 0; o < 4; ++o) {
        acc01[o] = (f32x2){0.f, 0.f};
        num2[o] = 0.f; den[o] = 0.f;
    }

    #pragma unroll 1
    for (int xs = -5; xs <= 5; ++xs) {
        const int jc  = jl - xs - 2;   // shifted 5-window base col
        const int xjc = jl - xs;       // shifted x neighbor col (ldsX)

        h2     swP[8][3];              // shifted-y f16-pair ring over rows
        float  Wr[4];                  // V-table ring
        float4 xw[4];                  // x-neighbor ring

        #pragma unroll
        for (int t = 0; t < 8; ++t) {
            int base = (il - 7 + t) * YSTR + jc;
            swP[t][0] = __builtin_bit_cast(h2, ldsY2[base]);
            swP[t][1] = __builtin_bit_cast(h2, ldsY2[base + 2]);
            swP[t][2] = __builtin_bit_cast(h2, ldsY2[base + 4]);
        }
        #pragma unroll
        for (int t = 0; t < 4; ++t) {
            Wr[t] = ldsV[(il - 7 + t) * VSTR + jc];
            xw[t] = ldsX[(il - 5 + t) * XD + xjc];
        }

        float  pd2[4];                 // pending d2 (weight tail deferred 1 step)
        float4 pxv;                    // snapshot of xw slot overwritten by commit

        #pragma unroll
        for (int k = 0; k <= 10; ++k) {     // ys = 5 - k
            // prefetch next step's ring entries
            h2 nsw0, nsw1, nsw2; float nWv; float4 nxw;
            if (k < 10) {
                const int nr = il + k + 1;
                int base = nr * YSTR + jc;
                nsw0 = __builtin_bit_cast(h2, ldsY2[base]);
                nsw1 = __builtin_bit_cast(h2, ldsY2[base + 2]);
                nsw2 = __builtin_bit_cast(h2, ldsY2[base + 4]);
                nWv  = ldsV[(il + k - 3) * VSTR + jc];
                nxw  = ldsX[(il + k - 1) * XD + xjc];
            }

            // row-dot cross terms (f16 MACs, f32 accumulate)
            float s[8];
            #pragma unroll
            for (int t = 0; t < 8; ++t) {
                const int m = (t + k) & 7;
                s[t] = fdot2(cyP[t][0], swP[m][0],
                       fdot2(cyP[t][1], swP[m][1],
                       fdot2(cyP[t][2], swP[m][2], 0.f)));
            }

            // sliding 5-row sums of cross terms
            float S0 = ((s[0] + s[1]) + (s[2] + s[3])) + s[4];
            float S1 = S0 - s[0] + s[5];
            float S2 = S1 - s[1] + s[6];
            float S3 = S2 - s[2] + s[7];

            float d2a[4];
            d2a[0] = fmaf(N2K2, S0, Vc[0] + Wr[k & 3]);
            d2a[1] = fmaf(N2K2, S1, Vc[1] + Wr[(k + 1) & 3]);
            d2a[2] = fmaf(N2K2, S2, Vc[2] + Wr[(k + 2) & 3]);
            d2a[3] = fmaf(N2K2, S3, Vc[3] + Wr[(k + 3) & 3]);

            // ---- deferred weight tail for step k-1 ----
            if (k > 0) {
                #pragma unroll
                for (int o = 0; o < 4; ++o) {
                    float4 xv = (o == 0) ? pxv : xw[(k - 1 + o) & 3];
                    float sd = __builtin_amdgcn_sqrtf(__builtin_fabsf(pd2[o]));
                    float w  = fast_exp2(-sd);
                    f32x2 bw = {w, w};
                    f32x2 xv01 = {xv.x, xv.y};
                    acc01[o] = __builtin_elementwise_fma(bw, xv01, acc01[o]);
                    num2[o] = fmaf(w, xv.z, num2[o]);
                    den[o] += w;
                }
            }

            // stage current step into pending; commit prefetched ring entries
            #pragma unroll
            for (int o = 0; o < 4; ++o) pd2[o] = d2a[o];
            if (k < 10) {
                pxv = xw[k & 3];
                swP[k & 7][0] = nsw0;
                swP[k & 7][1] = nsw1;
                swP[k & 7][2] = nsw2;
                Wr[k & 3] = nWv;
                xw[k & 3] = nxw;
            }
        }

        // ---- flush tail for k=10 (ring not overwritten at k=10) ----
        #pragma unroll
        for (int o = 0; o < 4; ++o) {
            float4 xv = xw[(10 + o) & 3];
            float sd = __builtin_amdgcn_sqrtf(__builtin_fabsf(pd2[o]));
            float w  = fast_exp2(-sd);
            f32x2 bw = {w, w};
            f32x2 xv01 = {xv.x, xv.y};
            acc01[o] = __builtin_elementwise_fma(bw, xv01, acc01[o]);
            num2[o] = fmaf(w, xv.z, num2[o]);
            den[o] += w;
        }
    }

    // ---- epilogue ----
    float* ob = out + (size_t)n * 3 * HWSZ;
    #pragma unroll
    for (int o = 0; o < 4; ++o) {
        int gi = ti + ty * 4 + o;
        int gj = tj + tx;
        size_t off = (size_t)gi * W_IMG + gj;
        float inv = __builtin_amdgcn_rcpf(den[o]);
        float v0 = fminf(fmaxf(acc01[o].x * inv, 0.f), 1.f);
        float v1 = fminf(fmaxf(acc01[o].y * inv, 0.f), 1.f);
        float v2 = fminf(fmaxf(num2[o]   * inv, 0.f), 1.f);
        ob[off]            = v0;
        ob[off + HWSZ]     = v1;
        ob[off + 2 * HWSZ] = v2;
    }
}

extern "C" void kernel_launch(void* const* d_in, const int* in_sizes, int n_in,
                              void* d_out, int out_size, void* d_ws, size_t ws_size,
                              hipStream_t stream) {
    const float* x = (const float*)d_in[0];
    float* out = (float*)d_out;
    dim3 grid(W_IMG / TILE, H_IMG / TILE, 2);   // (16,16,2) = 512 blocks
    dim3 block(32, 8);                          // 256 threads, mc=4
    nlm_kernel<<<grid, block, 0, stream>>>(x, out);
}